// Round 1
// baseline (4564.643 us; speedup 1.0000x reference)
//
#include <hip/hip_runtime.h>
#include <hip/hip_bf16.h>
#include <math.h>

// Problem: Elman RNN. T=256, B=128, INP=1024, HS=1024, OUT=1024.
// out = (scan_t tanh(x_t@W_ih + h@W_hh + b)) @ W_out.T + b_out
//
// Plan:
//  1) gemm_xw:   P[t,b,n] = data@W_ih + (b_i+b_h)  (bf16, 64MB ws)  -- one big MFMA GEMM
//  2) rnn_scan:  persistent 32-block kernel, 256 steps. K-split (Kg=4) x N-split (Ng=8).
//                W_hh slice resident in LDS (64KB, XOR-swizzled). fp32 partials -> grid
//                barrier -> reduce+tanh -> h_next (bf16) -> barrier.
//  3) gemm_out:  out = h_final @ W_out.T + b_out (fp32 out)

typedef __attribute__((ext_vector_type(8))) short bf16x8;
typedef __attribute__((ext_vector_type(4))) float f32x4;
typedef __attribute__((ext_vector_type(4))) unsigned short u16x4;

#define TT 256
#define BB 128
#define HS 1024
#define H_ELEMS (BB * HS)          // 131072

__device__ __forceinline__ short f2bf(float x) {
  __hip_bfloat16 b = __float2bfloat16(x);
  return *reinterpret_cast<short*>(&b);
}
__device__ __forceinline__ float bf2f(unsigned short s) {
  unsigned int u = ((unsigned int)s) << 16;
  float f;
  __builtin_memcpy(&f, &u, 4);
  return f;
}

// ---------------------------------------------------------------------------
// Kernel 1: P = data @ W_ih + (b_i + b_h), stored bf16.
// M=32768, N=1024, K=1024. 128x128 block tile, 4 waves of 64x64, K-chunk 64.
// ---------------------------------------------------------------------------
__global__ __launch_bounds__(256) void gemm_xw(
    const float* __restrict__ A,    // data [32768][1024]
    const float* __restrict__ B,    // W_ih [1024][1024] (k-major)
    const float* __restrict__ b_i,
    const float* __restrict__ b_h,
    __hip_bfloat16* __restrict__ P) {
  __shared__ __hip_bfloat16 As[128][72];  // [m][k], pad 64->72 (bank-spread)
  __shared__ __hip_bfloat16 Bs[128][72];  // [n][k] transposed, pad 64->72

  const int tid = threadIdx.x;
  const int m0 = blockIdx.y * 128, n0 = blockIdx.x * 128;
  const int wave = tid >> 6, lane = tid & 63;
  const int wm = wave & 1, wn = wave >> 1;
  const int quad = lane >> 4, l16 = lane & 15;

  f32x4 acc[4][4] = {};

  const int a_k4 = (tid & 15) * 4;  // 0..60
  const int a_m  = tid >> 4;        // 0..15
  const int b_n4 = (tid & 31) * 4;  // 0..124
  const int b_k  = tid >> 5;        // 0..7

  for (int k0 = 0; k0 < 1024; k0 += 64) {
    __syncthreads();
    // stage A tile (128 x 64), coalesced float4, convert to bf16
#pragma unroll
    for (int rep = 0; rep < 8; ++rep) {
      int ml = a_m + rep * 16;
      f32x4 v = *reinterpret_cast<const f32x4*>(A + (size_t)(m0 + ml) * 1024 + k0 + a_k4);
      u16x4 p;
      p[0] = (unsigned short)f2bf(v[0]);
      p[1] = (unsigned short)f2bf(v[1]);
      p[2] = (unsigned short)f2bf(v[2]);
      p[3] = (unsigned short)f2bf(v[3]);
      *reinterpret_cast<u16x4*>(&As[ml][a_k4]) = p;
    }
    // stage B tile (64k x 128n), transposed into Bs[n][k]
#pragma unroll
    for (int rep = 0; rep < 8; ++rep) {
      int kl = b_k + rep * 8;
      f32x4 v = *reinterpret_cast<const f32x4*>(B + (size_t)(k0 + kl) * 1024 + n0 + b_n4);
      Bs[b_n4 + 0][kl] = __float2bfloat16(v[0]);
      Bs[b_n4 + 1][kl] = __float2bfloat16(v[1]);
      Bs[b_n4 + 2][kl] = __float2bfloat16(v[2]);
      Bs[b_n4 + 3][kl] = __float2bfloat16(v[3]);
    }
    __syncthreads();
#pragma unroll
    for (int kk = 0; kk < 2; ++kk) {
      bf16x8 af[4], bfr[4];
#pragma unroll
      for (int mi = 0; mi < 4; ++mi)
        af[mi] = *reinterpret_cast<const bf16x8*>(&As[wm * 64 + mi * 16 + l16][kk * 32 + quad * 8]);
#pragma unroll
      for (int ni = 0; ni < 4; ++ni)
        bfr[ni] = *reinterpret_cast<const bf16x8*>(&Bs[wn * 64 + ni * 16 + l16][kk * 32 + quad * 8]);
#pragma unroll
      for (int mi = 0; mi < 4; ++mi)
#pragma unroll
        for (int ni = 0; ni < 4; ++ni)
          acc[mi][ni] = __builtin_amdgcn_mfma_f32_16x16x32_bf16(af[mi], bfr[ni], acc[mi][ni], 0, 0, 0);
    }
  }

  float bias[4];
#pragma unroll
  for (int ni = 0; ni < 4; ++ni) {
    int col = n0 + wn * 64 + ni * 16 + l16;
    bias[ni] = b_i[col] + b_h[col];
  }
#pragma unroll
  for (int mi = 0; mi < 4; ++mi)
#pragma unroll
    for (int ni = 0; ni < 4; ++ni) {
      int row = m0 + wm * 64 + mi * 16 + quad * 4;
      int col = n0 + wn * 64 + ni * 16 + l16;
#pragma unroll
      for (int r = 0; r < 4; ++r)
        P[(size_t)(row + r) * 1024 + col] = __float2bfloat16(acc[mi][ni][r] + bias[ni]);
    }
}

// ---------------------------------------------------------------------------
// Grid barrier: monotonic counter, device-scope. All 32 blocks co-resident.
// ---------------------------------------------------------------------------
__device__ __forceinline__ void gbar(unsigned* cnt, unsigned target) {
  __syncthreads();
  if (threadIdx.x == 0) {
    __threadfence();          // release prior stores (agent scope)
    atomicAdd(cnt, 1u);
    int guard = 0;
    while (__hip_atomic_load(cnt, __ATOMIC_RELAXED, __HIP_MEMORY_SCOPE_AGENT) < target) {
      __builtin_amdgcn_s_sleep(1);
      if (++guard > (1 << 20)) break;  // safety: no infinite hang
    }
    __threadfence();          // acquire
  }
  __syncthreads();
}

// ---------------------------------------------------------------------------
// Kernel 2: persistent scan. Grid = 32 blocks (kg = blk>>3 in [0,4), ng = blk&7).
// Each block: W_hh[kg*256..+256][ng*128..+128] resident in LDS (bf16, swizzled).
// Per step: partial[kg] = h[:, kgslice] @ Whh_slice  (128x128 fp32) -> barrier ->
//           h_next = tanh(sum_kg partial + P_t)      -> barrier.
// ---------------------------------------------------------------------------
__global__ __launch_bounds__(256) void rnn_scan(
    const __hip_bfloat16* __restrict__ P,   // [256][131072]
    const float* __restrict__ W_hh,         // [1024][1024] (k-major)
    __hip_bfloat16* __restrict__ hbuf,      // [2][131072], pre-zeroed
    float* __restrict__ part,               // [4][131072]
    unsigned* __restrict__ cnt) {           // pre-zeroed
  __shared__ __hip_bfloat16 Wt[128 * 256];  // [n_local][k_local], XOR-swizzled, 64KB

  const int tid = threadIdx.x;
  const int kg = blockIdx.x >> 3, ng = blockIdx.x & 7;

  // Load resident W_hh slice, transpose into Wt[n][k] with 16B-group swizzle:
  // group(k>>3) ^= (n&7)  -> ds_read_b128 frag reads land on distinct bank-quads.
  for (int i = tid; i < 128 * 256; i += 256) {
    int nl = i & 127, kl = i >> 7;  // consecutive tid -> consecutive n (coalesced global)
    int sg = (kl >> 3) ^ (nl & 7);
    Wt[nl * 256 + sg * 8 + (kl & 7)] =
        __float2bfloat16(W_hh[(size_t)(kg * 256 + kl) * 1024 + ng * 128 + nl]);
  }
  __syncthreads();

  const int wave = tid >> 6, lane = tid & 63;
  const int wm = wave & 1, wn = wave >> 1;   // wave tile 64x64 within 128x128
  const int quad = lane >> 4, l16 = lane & 15;
  const int g = blockIdx.x * 256 + tid;      // 0..8191 (phase B work id)
  unsigned target = 0;

  for (int t = 0; t < TT; ++t) {
    const __hip_bfloat16* hc = hbuf + (size_t)(t & 1) * H_ELEMS;

    // ---- phase A: partial GEMM over this block's K slice ----
    f32x4 acc[4][4] = {};
#pragma unroll
    for (int kk = 0; kk < 8; ++kk) {
      bf16x8 af[4], bfr[4];
#pragma unroll
      for (int mi = 0; mi < 4; ++mi)
        af[mi] = *reinterpret_cast<const bf16x8*>(
            hc + (size_t)(wm * 64 + mi * 16 + l16) * 1024 + kg * 256 + kk * 32 + quad * 8);
#pragma unroll
      for (int ni = 0; ni < 4; ++ni) {
        int n = wn * 64 + ni * 16 + l16;
        int sg = (kk * 4 + quad) ^ (n & 7);
        bfr[ni] = *reinterpret_cast<const bf16x8*>(Wt + n * 256 + sg * 8);
      }
#pragma unroll
      for (int mi = 0; mi < 4; ++mi)
#pragma unroll
        for (int ni = 0; ni < 4; ++ni)
          acc[mi][ni] = __builtin_amdgcn_mfma_f32_16x16x32_bf16(af[mi], bfr[ni], acc[mi][ni], 0, 0, 0);
    }
    {
      float* pk = part + (size_t)kg * H_ELEMS;
#pragma unroll
      for (int mi = 0; mi < 4; ++mi)
#pragma unroll
        for (int ni = 0; ni < 4; ++ni) {
          int row = wm * 64 + mi * 16 + quad * 4;
          int col = ng * 128 + wn * 64 + ni * 16 + l16;
#pragma unroll
          for (int r = 0; r < 4; ++r)
            pk[(size_t)(row + r) * 1024 + col] = acc[mi][ni][r];
        }
    }
    target += 32;
    gbar(cnt, target);

    // ---- phase B: reduce partials + P_t, tanh, write h_next ----
    {
      __hip_bfloat16* hn = hbuf + (size_t)((t + 1) & 1) * H_ELEMS;
      const __hip_bfloat16* Pt = P + (size_t)t * H_ELEMS;
#pragma unroll
      for (int v = 0; v < 4; ++v) {
        int idx = g * 4 + v * 32768;  // coalesced float4 per v-chunk
        f32x4 s = *reinterpret_cast<const f32x4*>(part + idx);
        s += *reinterpret_cast<const f32x4*>(part + H_ELEMS + idx);
        s += *reinterpret_cast<const f32x4*>(part + 2 * H_ELEMS + idx);
        s += *reinterpret_cast<const f32x4*>(part + 3 * H_ELEMS + idx);
        u16x4 pu = *reinterpret_cast<const u16x4*>(Pt + idx);
        s[0] += bf2f(pu[0]);
        s[1] += bf2f(pu[1]);
        s[2] += bf2f(pu[2]);
        s[3] += bf2f(pu[3]);
        u16x4 hv;
        hv[0] = (unsigned short)f2bf(tanhf(s[0]));
        hv[1] = (unsigned short)f2bf(tanhf(s[1]));
        hv[2] = (unsigned short)f2bf(tanhf(s[2]));
        hv[3] = (unsigned short)f2bf(tanhf(s[3]));
        *reinterpret_cast<u16x4*>(hn + idx) = hv;
      }
    }
    target += 32;
    gbar(cnt, target);
  }
}

// ---------------------------------------------------------------------------
// Kernel 3: out = h_final @ W_out.T + b_out. M=128, N(=O)=1024, K=1024.
// 16 blocks x 4 waves; wave tile 128M x 16O. B-frag built from fp32 W_out rows.
// ---------------------------------------------------------------------------
__global__ __launch_bounds__(256) void gemm_out(
    const __hip_bfloat16* __restrict__ h,   // [128][1024] (hbuf slot 0)
    const float* __restrict__ W_out,        // [1024][1024] row-major [o][k]
    const float* __restrict__ b_out,
    float* __restrict__ out) {              // [128][1024] fp32
  const int tid = threadIdx.x;
  const int wave = tid >> 6, lane = tid & 63;
  const int quad = lane >> 4, l16 = lane & 15;
  const int o = blockIdx.x * 64 + wave * 16 + l16;

  f32x4 acc[8] = {};
  for (int k0 = 0; k0 < 1024; k0 += 32) {
    f32x4 w0 = *reinterpret_cast<const f32x4*>(W_out + (size_t)o * 1024 + k0 + quad * 8);
    f32x4 w1 = *reinterpret_cast<const f32x4*>(W_out + (size_t)o * 1024 + k0 + quad * 8 + 4);
    bf16x8 bfr;
    bfr[0] = f2bf(w0[0]); bfr[1] = f2bf(w0[1]); bfr[2] = f2bf(w0[2]); bfr[3] = f2bf(w0[3]);
    bfr[4] = f2bf(w1[0]); bfr[5] = f2bf(w1[1]); bfr[6] = f2bf(w1[2]); bfr[7] = f2bf(w1[3]);
#pragma unroll
    for (int mi = 0; mi < 8; ++mi) {
      bf16x8 af = *reinterpret_cast<const bf16x8*>(h + (size_t)(mi * 16 + l16) * 1024 + k0 + quad * 8);
      acc[mi] = __builtin_amdgcn_mfma_f32_16x16x32_bf16(af, bfr, acc[mi], 0, 0, 0);
    }
  }
  const float bias = b_out[o];
#pragma unroll
  for (int mi = 0; mi < 8; ++mi)
#pragma unroll
    for (int r = 0; r < 4; ++r)
      out[(size_t)(mi * 16 + quad * 4 + r) * 1024 + o] = acc[mi][r] + bias;
}

// ---------------------------------------------------------------------------
// Workspace layout (bytes):
//   [0, 64MB)                 P (bf16, 256*131072)
//   [64MB, +512KB)            h double buffer (bf16, 2*131072)
//   [.., +256B)               barrier counter
//   [.., +2MB)                partials (fp32, 4*131072)
// Total ~66.5 MB.
// ---------------------------------------------------------------------------
extern "C" void kernel_launch(void* const* d_in, const int* in_sizes, int n_in,
                              void* d_out, int out_size, void* d_ws, size_t ws_size,
                              hipStream_t stream) {
  const float* data  = (const float*)d_in[0];
  const float* W_ih  = (const float*)d_in[1];
  const float* W_hh  = (const float*)d_in[2];
  const float* b_i   = (const float*)d_in[3];
  const float* b_h   = (const float*)d_in[4];
  const float* W_out = (const float*)d_in[5];
  const float* b_out = (const float*)d_in[6];
  float* out = (float*)d_out;

  char* ws = (char*)d_ws;
  const size_t OFF_P    = 0;
  const size_t OFF_H    = (size_t)TT * H_ELEMS * 2;        // 67,108,864
  const size_t OFF_CNT  = OFF_H + 2 * H_ELEMS * 2;         // +524,288
  const size_t OFF_PART = OFF_CNT + 256;

  __hip_bfloat16* P    = (__hip_bfloat16*)(ws + OFF_P);
  __hip_bfloat16* hbuf = (__hip_bfloat16*)(ws + OFF_H);
  unsigned* cnt        = (unsigned*)(ws + OFF_CNT);
  float* part          = (float*)(ws + OFF_PART);

  // zero h0/h1 + barrier counter (ws is poisoned 0xAA before every launch)
  hipMemsetAsync(ws + OFF_H, 0, 2 * H_ELEMS * 2 + 256, stream);

  gemm_xw<<<dim3(8, 256), 256, 0, stream>>>(data, W_ih, b_i, b_h, P);
  rnn_scan<<<32, 256, 0, stream>>>(P, W_hh, hbuf, part, cnt);
  gemm_out<<<16, 256, 0, stream>>>(hbuf, W_out, b_out, out);  // h_final in slot 0 (256 even)
}

// Round 2
// 4054.667 us; speedup vs baseline: 1.1258x; 1.1258x over previous
//
#include <hip/hip_runtime.h>
#include <hip/hip_bf16.h>
#include <math.h>

// Elman RNN. T=256, B=128, INP=HS=OUT=1024.
//  1) gemm_xw:   P[t,b,n] = data@W_ih + (b_i+b_h)  (bf16, 64MB ws)
//  2) rnn_scan2: persistent 256-block kernel. Batch-split (8 groups x 16 rows)
//                x N-split (32 slices x 32 cols). W_hh[:,slice] resident in LDS.
//                ONE group-local barrier per step (groups of 32 blocks, disjoint
//                h rows -> no cross-group sync). No partial-matrix round trip.
//  3) gemm_out:  out = h_final @ W_out.T + b_out (fp32)

typedef __attribute__((ext_vector_type(8))) short bf16x8;
typedef __attribute__((ext_vector_type(4))) float f32x4;
typedef __attribute__((ext_vector_type(4))) unsigned short u16x4;

#define TT 256
#define BB 128
#define HS 1024
#define H_ELEMS (BB * HS)          // 131072

__device__ __forceinline__ short f2bf(float x) {
  __hip_bfloat16 b = __float2bfloat16(x);
  return *reinterpret_cast<short*>(&b);
}
__device__ __forceinline__ float bf2f(unsigned short s) {
  unsigned int u = ((unsigned int)s) << 16;
  float f;
  __builtin_memcpy(&f, &u, 4);
  return f;
}
__device__ __forceinline__ float fast_exp2(float x) {
#if __has_builtin(__builtin_amdgcn_exp2f)
  return __builtin_amdgcn_exp2f(x);
#else
  return exp2f(x);
#endif
}
__device__ __forceinline__ float fast_rcp(float x) {
#if __has_builtin(__builtin_amdgcn_rcpf)
  return __builtin_amdgcn_rcpf(x);
#else
  return 1.0f / x;
#endif
}
// tanh(x) = (e-1)/(e+1), e = 2^(x * 2*log2(e)); clamp keeps e finite.
__device__ __forceinline__ float fast_tanh(float x) {
  float xc = fminf(fmaxf(x, -9.0f), 9.0f);
  float e = fast_exp2(2.8853900817779268f * xc);
  return (e - 1.0f) * fast_rcp(e + 1.0f);
}

// ---------------------------------------------------------------------------
// Kernel 1: P = data @ W_ih + (b_i + b_h), stored bf16.  (unchanged, validated)
// ---------------------------------------------------------------------------
__global__ __launch_bounds__(256) void gemm_xw(
    const float* __restrict__ A,    // data [32768][1024]
    const float* __restrict__ B,    // W_ih [1024][1024] (k-major)
    const float* __restrict__ b_i,
    const float* __restrict__ b_h,
    __hip_bfloat16* __restrict__ P) {
  __shared__ __hip_bfloat16 As[128][72];
  __shared__ __hip_bfloat16 Bs[128][72];

  const int tid = threadIdx.x;
  const int m0 = blockIdx.y * 128, n0 = blockIdx.x * 128;
  const int wave = tid >> 6, lane = tid & 63;
  const int wm = wave & 1, wn = wave >> 1;
  const int quad = lane >> 4, l16 = lane & 15;

  f32x4 acc[4][4] = {};

  const int a_k4 = (tid & 15) * 4;
  const int a_m  = tid >> 4;
  const int b_n4 = (tid & 31) * 4;
  const int b_k  = tid >> 5;

  for (int k0 = 0; k0 < 1024; k0 += 64) {
    __syncthreads();
#pragma unroll
    for (int rep = 0; rep < 8; ++rep) {
      int ml = a_m + rep * 16;
      f32x4 v = *reinterpret_cast<const f32x4*>(A + (size_t)(m0 + ml) * 1024 + k0 + a_k4);
      u16x4 p;
      p[0] = (unsigned short)f2bf(v[0]);
      p[1] = (unsigned short)f2bf(v[1]);
      p[2] = (unsigned short)f2bf(v[2]);
      p[3] = (unsigned short)f2bf(v[3]);
      *reinterpret_cast<u16x4*>(&As[ml][a_k4]) = p;
    }
#pragma unroll
    for (int rep = 0; rep < 8; ++rep) {
      int kl = b_k + rep * 8;
      f32x4 v = *reinterpret_cast<const f32x4*>(B + (size_t)(k0 + kl) * 1024 + n0 + b_n4);
      Bs[b_n4 + 0][kl] = __float2bfloat16(v[0]);
      Bs[b_n4 + 1][kl] = __float2bfloat16(v[1]);
      Bs[b_n4 + 2][kl] = __float2bfloat16(v[2]);
      Bs[b_n4 + 3][kl] = __float2bfloat16(v[3]);
    }
    __syncthreads();
#pragma unroll
    for (int kk = 0; kk < 2; ++kk) {
      bf16x8 af[4], bfr[4];
#pragma unroll
      for (int mi = 0; mi < 4; ++mi)
        af[mi] = *reinterpret_cast<const bf16x8*>(&As[wm * 64 + mi * 16 + l16][kk * 32 + quad * 8]);
#pragma unroll
      for (int ni = 0; ni < 4; ++ni)
        bfr[ni] = *reinterpret_cast<const bf16x8*>(&Bs[wn * 64 + ni * 16 + l16][kk * 32 + quad * 8]);
#pragma unroll
      for (int mi = 0; mi < 4; ++mi)
#pragma unroll
        for (int ni = 0; ni < 4; ++ni)
          acc[mi][ni] = __builtin_amdgcn_mfma_f32_16x16x32_bf16(af[mi], bfr[ni], acc[mi][ni], 0, 0, 0);
    }
  }

  float bias[4];
#pragma unroll
  for (int ni = 0; ni < 4; ++ni) {
    int col = n0 + wn * 64 + ni * 16 + l16;
    bias[ni] = b_i[col] + b_h[col];
  }
#pragma unroll
  for (int mi = 0; mi < 4; ++mi)
#pragma unroll
    for (int ni = 0; ni < 4; ++ni) {
      int row = m0 + wm * 64 + mi * 16 + quad * 4;
      int col = n0 + wn * 64 + ni * 16 + l16;
#pragma unroll
      for (int r = 0; r < 4; ++r)
        P[(size_t)(row + r) * 1024 + col] = __float2bfloat16(acc[mi][ni][r] + bias[ni]);
    }
}

// ---------------------------------------------------------------------------
// Group barrier: monotonic per-group counter, device scope.
// ---------------------------------------------------------------------------
__device__ __forceinline__ void gbar(unsigned* cnt, unsigned target) {
  __syncthreads();   // waits vmcnt(0): all block stores issued & drained
  if (threadIdx.x == 0) {
    __threadfence();          // release
    atomicAdd(cnt, 1u);
    int guard = 0;
    while (__hip_atomic_load(cnt, __ATOMIC_RELAXED, __HIP_MEMORY_SCOPE_AGENT) < target) {
      __builtin_amdgcn_s_sleep(1);
      if (++guard > (1 << 20)) break;  // safety: no infinite hang
    }
    __threadfence();          // acquire
  }
  __syncthreads();
}

// ---------------------------------------------------------------------------
// Kernel 2: persistent scan, 256 blocks x 128 threads (2 waves).
//   m-group = blockIdx & 7   (16 batch rows; same-XCD under round-robin)
//   n-group = blockIdx >> 3  (32 hidden cols)
// LDS: Wt[nl 32][k 1024] bf16 = 64KB, XOR-swizzled 8-elem groups.
// Per step: h_next[m0..+16, n0..+32] = tanh(P_t + h @ Wslice); 1 barrier.
// Groups write disjoint h rows -> no cross-group sync. 2-buffer ping-pong is
// safe with one barrier/step (see analysis: h[t+2] reuses h[t]'s buffer only
// after every group member finished reading h[t]).
// ---------------------------------------------------------------------------
__global__ __launch_bounds__(128) void rnn_scan2(
    const __hip_bfloat16* __restrict__ P,   // [256][131072]
    const float* __restrict__ W_hh,         // [1024][1024] (k-major)
    __hip_bfloat16* __restrict__ hbuf,      // [2][131072], pre-zeroed
    unsigned* __restrict__ cnt) {           // 8 groups x 64 uints, pre-zeroed
  __shared__ __hip_bfloat16 Wt[32 * 1024];  // [n_local][k], swizzled, 64KB

  const int tid = threadIdx.x;
  const int m = blockIdx.x & 7;          // group id
  const int ng = blockIdx.x >> 3;        // 0..31
  const int m0 = m * 16, n0 = ng * 32;

  // Load resident W slice: Wt[nl][k] = W_hh[k][n0+nl]; swizzle sg=(k>>3)^(nl&7).
  // float4 global reads (coalesced); 2B LDS writes (~4-way, one-time).
  for (int i = tid; i < 32 * 1024 / 4; i += 128) {
    int nq = i & 7, k = i >> 3;
    f32x4 v = *reinterpret_cast<const f32x4*>(W_hh + (size_t)k * 1024 + n0 + nq * 4);
#pragma unroll
    for (int j = 0; j < 4; ++j) {
      int nl = nq * 4 + j;
      int sg = (k >> 3) ^ (nl & 7);
      Wt[nl * 1024 + sg * 8 + (k & 7)] = __float2bfloat16(v[j]);
    }
  }
  __syncthreads();

  const int w = tid >> 6, lane = tid & 63;
  const int quad = lane >> 4, l16 = lane & 15;
  const int nl = w * 16 + l16;           // this wave's n within block slice
  const int col = n0 + nl;
  unsigned* mycnt = cnt + m * 64;        // 256B-spaced per-group counters
  unsigned target = 0;

  for (int t = 0; t < TT; ++t) {
    const __hip_bfloat16* hc = hbuf + (size_t)(t & 1) * H_ELEMS;
    __hip_bfloat16* hn = hbuf + (size_t)((t + 1) & 1) * H_ELEMS;
    const __hip_bfloat16* hrow = hc + (size_t)(m0 + l16) * 1024 + quad * 8;

    // prefetch P_t operands (independent of the k-loop)
    const __hip_bfloat16* Pt =
        P + (size_t)t * H_ELEMS + (size_t)(m0 + quad * 4) * 1024 + col;
    unsigned short pv[4];
#pragma unroll
    for (int r = 0; r < 4; ++r)
      pv[r] = *reinterpret_cast<const unsigned short*>(Pt + (size_t)r * 1024);

    // k-loop: 32 MFMAs (16x16x32), A from global (double-buffered), B from LDS.
    f32x4 acc[4] = {{0.f, 0.f, 0.f, 0.f}, {0.f, 0.f, 0.f, 0.f},
                    {0.f, 0.f, 0.f, 0.f}, {0.f, 0.f, 0.f, 0.f}};
    bf16x8 a0[4], a1[4];
#pragma unroll
    for (int j = 0; j < 4; ++j)
      a0[j] = *reinterpret_cast<const bf16x8*>(hrow + j * 32);
#pragma unroll
    for (int c = 0; c < 8; ++c) {
      const bf16x8* cur = (c & 1) ? a1 : a0;
      bf16x8* nxt = (c & 1) ? a0 : a1;
      if (c < 7) {
#pragma unroll
        for (int j = 0; j < 4; ++j)
          nxt[j] = *reinterpret_cast<const bf16x8*>(hrow + (c + 1) * 128 + j * 32);
      }
#pragma unroll
      for (int j = 0; j < 4; ++j) {
        int kg = (c * 4 + j) * 4 + quad;       // k>>3 group index
        int sg = kg ^ (nl & 7);
        bf16x8 bfrag = *reinterpret_cast<const bf16x8*>(Wt + (size_t)nl * 1024 + sg * 8);
        acc[j] = __builtin_amdgcn_mfma_f32_16x16x32_bf16(cur[j], bfrag, acc[j], 0, 0, 0);
      }
    }

    // epilogue: reduce 4 accs, add P_t, tanh, store bf16 h_next
#pragma unroll
    for (int r = 0; r < 4; ++r) {
      float s = (acc[0][r] + acc[1][r]) + (acc[2][r] + acc[3][r]) + bf2f(pv[r]);
      float th = fast_tanh(s);
      *reinterpret_cast<unsigned short*>(
          hn + (size_t)(m0 + quad * 4 + r) * 1024 + col) = (unsigned short)f2bf(th);
    }

    if (t != TT - 1) {
      target += 32;            // 32 blocks per group
      gbar(mycnt, target);
    }
  }
}

// ---------------------------------------------------------------------------
// Kernel 3: out = h_final @ W_out.T + b_out.  (unchanged, validated)
// ---------------------------------------------------------------------------
__global__ __launch_bounds__(256) void gemm_out(
    const __hip_bfloat16* __restrict__ h,   // [128][1024] (hbuf slot 0)
    const float* __restrict__ W_out,        // [1024][1024] row-major [o][k]
    const float* __restrict__ b_out,
    float* __restrict__ out) {              // [128][1024] fp32
  const int tid = threadIdx.x;
  const int wave = tid >> 6, lane = tid & 63;
  const int quad = lane >> 4, l16 = lane & 15;
  const int o = blockIdx.x * 64 + wave * 16 + l16;

  f32x4 acc[8] = {};
  for (int k0 = 0; k0 < 1024; k0 += 32) {
    f32x4 w0 = *reinterpret_cast<const f32x4*>(W_out + (size_t)o * 1024 + k0 + quad * 8);
    f32x4 w1 = *reinterpret_cast<const f32x4*>(W_out + (size_t)o * 1024 + k0 + quad * 8 + 4);
    bf16x8 bfr;
    bfr[0] = f2bf(w0[0]); bfr[1] = f2bf(w0[1]); bfr[2] = f2bf(w0[2]); bfr[3] = f2bf(w0[3]);
    bfr[4] = f2bf(w1[0]); bfr[5] = f2bf(w1[1]); bfr[6] = f2bf(w1[2]); bfr[7] = f2bf(w1[3]);
#pragma unroll
    for (int mi = 0; mi < 8; ++mi) {
      bf16x8 af = *reinterpret_cast<const bf16x8*>(h + (size_t)(mi * 16 + l16) * 1024 + k0 + quad * 8);
      acc[mi] = __builtin_amdgcn_mfma_f32_16x16x32_bf16(af, bfr, acc[mi], 0, 0, 0);
    }
  }
  const float bias = b_out[o];
#pragma unroll
  for (int mi = 0; mi < 8; ++mi)
#pragma unroll
    for (int r = 0; r < 4; ++r)
      out[(size_t)(mi * 16 + quad * 4 + r) * 1024 + o] = acc[mi][r] + bias;
}

// ---------------------------------------------------------------------------
// Workspace: [0,64MB) P bf16 | +512KB h double buffer | +2KB group counters
// ---------------------------------------------------------------------------
extern "C" void kernel_launch(void* const* d_in, const int* in_sizes, int n_in,
                              void* d_out, int out_size, void* d_ws, size_t ws_size,
                              hipStream_t stream) {
  const float* data  = (const float*)d_in[0];
  const float* W_ih  = (const float*)d_in[1];
  const float* W_hh  = (const float*)d_in[2];
  const float* b_i   = (const float*)d_in[3];
  const float* b_h   = (const float*)d_in[4];
  const float* W_out = (const float*)d_in[5];
  const float* b_out = (const float*)d_in[6];
  float* out = (float*)d_out;

  char* ws = (char*)d_ws;
  const size_t OFF_P   = 0;
  const size_t OFF_H   = (size_t)TT * H_ELEMS * 2;   // 67,108,864
  const size_t OFF_CNT = OFF_H + 2 * H_ELEMS * 2;    // +524,288

  __hip_bfloat16* P    = (__hip_bfloat16*)(ws + OFF_P);
  __hip_bfloat16* hbuf = (__hip_bfloat16*)(ws + OFF_H);
  unsigned* cnt        = (unsigned*)(ws + OFF_CNT);

  // zero h0/h1 + group counters (ws is poisoned 0xAA before every launch)
  hipMemsetAsync(ws + OFF_H, 0, 2 * H_ELEMS * 2 + 2048, stream);

  gemm_xw<<<dim3(8, 256), 256, 0, stream>>>(data, W_ih, b_i, b_h, P);
  rnn_scan2<<<256, 128, 0, stream>>>(P, W_hh, hbuf, cnt);
  gemm_out<<<16, 256, 0, stream>>>(hbuf, W_out, b_out, out);  // h[256] in slot 0
}

// Round 3
// 1848.814 us; speedup vs baseline: 2.4690x; 2.1931x over previous
//
#include <hip/hip_runtime.h>
#include <hip/hip_bf16.h>
#include <math.h>

// Elman RNN. T=256, B=128, INP=HS=OUT=1024.
//  1) gemm_xw:   P[t,b,n] = data@W_ih + (b_i+b_h)  (bf16, 64MB ws)
//  2) rnn_scan3: persistent 256-block kernel, 8 m-groups x 32 n-slices.
//                FENCELESS sync: all cross-block data (h, flags) moves via
//                sc0 sc1 (MALL-direct) loads/stores -> no buffer_wbl2/inv.
//                Producer: h stores -> vmcnt(0) -> flag=t+1. Consumer: poll
//                32 flags >= t -> bulk-load h tile into LDS -> MFMA.
//  3) gemm_out:  out = h_final @ W_out.T + b_out (fp32)

typedef __attribute__((ext_vector_type(8))) short bf16x8;
typedef __attribute__((ext_vector_type(4))) float f32x4;
typedef __attribute__((ext_vector_type(4))) unsigned short u16x4;
typedef __attribute__((ext_vector_type(4))) unsigned int u32x4;
typedef __attribute__((ext_vector_type(2))) unsigned int u32x2;

#define TT 256
#define BB 128
#define HS 1024
#define H_ELEMS (BB * HS)          // 131072
#define HP 1032                    // Ht LDS pitch (2-way bank alias = free)

__device__ __forceinline__ short f2bf(float x) {
  __hip_bfloat16 b = __float2bfloat16(x);
  return *reinterpret_cast<short*>(&b);
}
__device__ __forceinline__ float bf2f(unsigned short s) {
  unsigned int u = ((unsigned int)s) << 16;
  float f;
  __builtin_memcpy(&f, &u, 4);
  return f;
}
__device__ __forceinline__ float fast_exp2(float x) {
#if __has_builtin(__builtin_amdgcn_exp2f)
  return __builtin_amdgcn_exp2f(x);
#else
  return exp2f(x);
#endif
}
__device__ __forceinline__ float fast_rcp(float x) {
#if __has_builtin(__builtin_amdgcn_rcpf)
  return __builtin_amdgcn_rcpf(x);
#else
  return 1.0f / x;
#endif
}
__device__ __forceinline__ float fast_tanh(float x) {
  float xc = fminf(fmaxf(x, -9.0f), 9.0f);
  float e = fast_exp2(2.8853900817779268f * xc);
  return (e - 1.0f) * fast_rcp(e + 1.0f);
}

// ---- MALL-direct (coherence-point) memory ops: bypass L1+L2, no fences ----
__device__ __forceinline__ void mall_load_b128(u32x4* dst, const void* p) {
  asm volatile("global_load_dwordx4 %0, %1, off sc0 sc1" : "=v"(*dst) : "v"(p) : "memory");
}
__device__ __forceinline__ void mall_store_b64(void* p, u32x2 v) {
  asm volatile("global_store_dwordx2 %0, %1, off sc0 sc1" :: "v"(p), "v"(v) : "memory");
}
__device__ __forceinline__ void mall_store_b32(void* p, unsigned v) {
  asm volatile("global_store_dword %0, %1, off sc0 sc1" :: "v"(p), "v"(v) : "memory");
}
__device__ __forceinline__ unsigned mall_poll_b32(const void* p) {
  unsigned v;
  asm volatile("global_load_dword %0, %1, off sc0 sc1" : "=v"(v) : "v"(p) : "memory");
  asm volatile("s_waitcnt vmcnt(0)" : "+v"(v));
  return v;
}
__device__ __forceinline__ void wait_vm0() {
  asm volatile("s_waitcnt vmcnt(0)" ::: "memory");
}

// ---------------------------------------------------------------------------
// Kernel 1: P = data @ W_ih + (b_i + b_h), stored bf16.  (unchanged, validated)
// ---------------------------------------------------------------------------
__global__ __launch_bounds__(256) void gemm_xw(
    const float* __restrict__ A,    // data [32768][1024]
    const float* __restrict__ B,    // W_ih [1024][1024] (k-major)
    const float* __restrict__ b_i,
    const float* __restrict__ b_h,
    __hip_bfloat16* __restrict__ P) {
  __shared__ __hip_bfloat16 As[128][72];
  __shared__ __hip_bfloat16 Bs[128][72];

  const int tid = threadIdx.x;
  const int m0 = blockIdx.y * 128, n0 = blockIdx.x * 128;
  const int wave = tid >> 6, lane = tid & 63;
  const int wm = wave & 1, wn = wave >> 1;
  const int quad = lane >> 4, l16 = lane & 15;

  f32x4 acc[4][4] = {};

  const int a_k4 = (tid & 15) * 4;
  const int a_m  = tid >> 4;
  const int b_n4 = (tid & 31) * 4;
  const int b_k  = tid >> 5;

  for (int k0 = 0; k0 < 1024; k0 += 64) {
    __syncthreads();
#pragma unroll
    for (int rep = 0; rep < 8; ++rep) {
      int ml = a_m + rep * 16;
      f32x4 v = *reinterpret_cast<const f32x4*>(A + (size_t)(m0 + ml) * 1024 + k0 + a_k4);
      u16x4 p;
      p[0] = (unsigned short)f2bf(v[0]);
      p[1] = (unsigned short)f2bf(v[1]);
      p[2] = (unsigned short)f2bf(v[2]);
      p[3] = (unsigned short)f2bf(v[3]);
      *reinterpret_cast<u16x4*>(&As[ml][a_k4]) = p;
    }
#pragma unroll
    for (int rep = 0; rep < 8; ++rep) {
      int kl = b_k + rep * 8;
      f32x4 v = *reinterpret_cast<const f32x4*>(B + (size_t)(k0 + kl) * 1024 + n0 + b_n4);
      Bs[b_n4 + 0][kl] = __float2bfloat16(v[0]);
      Bs[b_n4 + 1][kl] = __float2bfloat16(v[1]);
      Bs[b_n4 + 2][kl] = __float2bfloat16(v[2]);
      Bs[b_n4 + 3][kl] = __float2bfloat16(v[3]);
    }
    __syncthreads();
#pragma unroll
    for (int kk = 0; kk < 2; ++kk) {
      bf16x8 af[4], bfr[4];
#pragma unroll
      for (int mi = 0; mi < 4; ++mi)
        af[mi] = *reinterpret_cast<const bf16x8*>(&As[wm * 64 + mi * 16 + l16][kk * 32 + quad * 8]);
#pragma unroll
      for (int ni = 0; ni < 4; ++ni)
        bfr[ni] = *reinterpret_cast<const bf16x8*>(&Bs[wn * 64 + ni * 16 + l16][kk * 32 + quad * 8]);
#pragma unroll
      for (int mi = 0; mi < 4; ++mi)
#pragma unroll
        for (int ni = 0; ni < 4; ++ni)
          acc[mi][ni] = __builtin_amdgcn_mfma_f32_16x16x32_bf16(af[mi], bfr[ni], acc[mi][ni], 0, 0, 0);
    }
  }

  float bias[4];
#pragma unroll
  for (int ni = 0; ni < 4; ++ni) {
    int col = n0 + wn * 64 + ni * 16 + l16;
    bias[ni] = b_i[col] + b_h[col];
  }
#pragma unroll
  for (int mi = 0; mi < 4; ++mi)
#pragma unroll
    for (int ni = 0; ni < 4; ++ni) {
      int row = m0 + wm * 64 + mi * 16 + quad * 4;
      int col = n0 + wn * 64 + ni * 16 + l16;
#pragma unroll
      for (int r = 0; r < 4; ++r)
        P[(size_t)(row + r) * 1024 + col] = __float2bfloat16(acc[mi][ni][r] + bias[ni]);
    }
}

// ---------------------------------------------------------------------------
// Kernel 2: persistent fenceless scan. 256 blocks x 128 threads.
//   m = blockIdx&7 (16 batch rows), ng = blockIdx>>3 (32 hidden cols).
// LDS: Wt 64KB resident W slice (swizzled) + Ht 33KB h tile + Cs 1.2KB stage.
// ---------------------------------------------------------------------------
__global__ __launch_bounds__(128) void rnn_scan3(
    const __hip_bfloat16* __restrict__ P,   // [256][131072]
    const float* __restrict__ W_hh,         // [1024][1024] (k-major)
    __hip_bfloat16* __restrict__ hbuf,      // [2][131072], pre-zeroed
    unsigned* __restrict__ flags) {         // [8][32], pre-zeroed
  __shared__ __hip_bfloat16 Wt[32 * 1024];  // [n_local][k], swizzled
  __shared__ __hip_bfloat16 Ht[16 * HP];    // h tile [row][k], pitch 1032
  __shared__ __hip_bfloat16 Cs[16 * 36];    // epilogue transpose staging

  const int tid = threadIdx.x;
  const int m = blockIdx.x & 7;
  const int ng = blockIdx.x >> 3;
  const int m0 = m * 16, n0 = ng * 32;

  // Resident W slice: Wt[nl][k] = W_hh[k][n0+nl]; swizzle sg=(k>>3)^(nl&7).
  for (int i = tid; i < 32 * 1024 / 4; i += 128) {
    int nq = i & 7, k = i >> 3;
    f32x4 v = *reinterpret_cast<const f32x4*>(W_hh + (size_t)k * 1024 + n0 + nq * 4);
#pragma unroll
    for (int j = 0; j < 4; ++j) {
      int nl = nq * 4 + j;
      int sg = (k >> 3) ^ (nl & 7);
      Wt[nl * 1024 + sg * 8 + (k & 7)] = __float2bfloat16(v[j]);
    }
  }

  const int w = tid >> 6, lane = tid & 63;
  const int quad = lane >> 4, l16 = lane & 15;
  const int nl = w * 16 + l16;
  const int col = n0 + nl;
  const int hrow = tid >> 3;          // 0..15 (h-tile load row)
  const int hcol0 = (tid & 7) * 128;  // 0..896 (h-tile load col seg)
  const int crow = tid >> 3, cseg = tid & 7;  // epilogue store mapping
  __syncthreads();

  for (int t = 0; t < TT; ++t) {
    const __hip_bfloat16* hc = hbuf + (size_t)(t & 1) * H_ELEMS;
    __hip_bfloat16* hn = hbuf + (size_t)((t + 1) & 1) * H_ELEMS;

    // ---- wait for h_t (all 32 producers of this m-group) ----
    if (t > 0 && tid < 32) {
      const unsigned* fp = flags + m * 32 + tid;
      int guard = 0;
      while (mall_poll_b32(fp) < (unsigned)t && ++guard < (1 << 18)) {}
    }
    __syncthreads();

    // ---- bulk-load h_t tile (32KB) via MALL-direct dwordx4 into LDS ----
    {
      const char* src = (const char*)(hc + (size_t)(m0 + hrow) * 1024 + hcol0);
      u32x4 d[16];
#pragma unroll
      for (int i = 0; i < 16; ++i) mall_load_b128(&d[i], src + i * 16);
      asm volatile("s_waitcnt vmcnt(0)"
                   : "+v"(d[0]), "+v"(d[1]), "+v"(d[2]), "+v"(d[3]),
                     "+v"(d[4]), "+v"(d[5]), "+v"(d[6]), "+v"(d[7]),
                     "+v"(d[8]), "+v"(d[9]), "+v"(d[10]), "+v"(d[11]),
                     "+v"(d[12]), "+v"(d[13]), "+v"(d[14]), "+v"(d[15]));
#pragma unroll
      for (int i = 0; i < 16; ++i)
        *reinterpret_cast<u32x4*>(&Ht[hrow * HP + hcol0 + i * 8]) = d[i];
    }

    // prefetch P_t operands (read-only, normal cached loads)
    const __hip_bfloat16* Pt =
        P + (size_t)t * H_ELEMS + (size_t)(m0 + quad * 4) * 1024 + col;
    unsigned short pv[4];
#pragma unroll
    for (int r = 0; r < 4; ++r)
      pv[r] = *reinterpret_cast<const unsigned short*>(Pt + (size_t)r * 1024);

    __syncthreads();

    // ---- MFMA: h_tile(16x1024) @ Wslice(1024x32) -> 16x32 ----
    f32x4 acc[4] = {{0.f, 0.f, 0.f, 0.f}, {0.f, 0.f, 0.f, 0.f},
                    {0.f, 0.f, 0.f, 0.f}, {0.f, 0.f, 0.f, 0.f}};
#pragma unroll
    for (int c = 0; c < 8; ++c) {
#pragma unroll
      for (int j = 0; j < 4; ++j) {
        bf16x8 af = *reinterpret_cast<const bf16x8*>(&Ht[l16 * HP + c * 128 + j * 32 + quad * 8]);
        int kg = (c * 4 + j) * 4 + quad;
        int sg = kg ^ (nl & 7);
        bf16x8 bfrag = *reinterpret_cast<const bf16x8*>(&Wt[nl * 1024 + sg * 8]);
        acc[j] = __builtin_amdgcn_mfma_f32_16x16x32_bf16(af, bfrag, acc[j], 0, 0, 0);
      }
    }

    // ---- epilogue: sum, +P, tanh -> stage (transpose) -> MALL store ----
#pragma unroll
    for (int r = 0; r < 4; ++r) {
      float s = (acc[0][r] + acc[1][r]) + (acc[2][r] + acc[3][r]) + bf2f(pv[r]);
      Cs[(quad * 4 + r) * 36 + nl] = __float2bfloat16(fast_tanh(s));
    }
    __syncthreads();
    {
      u32x2 val = *reinterpret_cast<const u32x2*>(&Cs[crow * 36 + cseg * 4]);
      mall_store_b64(hn + (size_t)(m0 + crow) * 1024 + n0 + cseg * 4, val);
      wait_vm0();  // h stores acked at MALL before flag
    }
    __syncthreads();  // all waves drained

    if (tid == 0) mall_store_b32(flags + m * 32 + ng, (unsigned)(t + 1));
  }
}

// ---------------------------------------------------------------------------
// Kernel 3: out = h_final @ W_out.T + b_out.  (unchanged, validated)
// ---------------------------------------------------------------------------
__global__ __launch_bounds__(256) void gemm_out(
    const __hip_bfloat16* __restrict__ h,   // [128][1024] (hbuf slot 0)
    const float* __restrict__ W_out,        // [1024][1024] row-major [o][k]
    const float* __restrict__ b_out,
    float* __restrict__ out) {              // [128][1024] fp32
  const int tid = threadIdx.x;
  const int wave = tid >> 6, lane = tid & 63;
  const int quad = lane >> 4, l16 = lane & 15;
  const int o = blockIdx.x * 64 + wave * 16 + l16;

  f32x4 acc[8] = {};
  for (int k0 = 0; k0 < 1024; k0 += 32) {
    f32x4 w0 = *reinterpret_cast<const f32x4*>(W_out + (size_t)o * 1024 + k0 + quad * 8);
    f32x4 w1 = *reinterpret_cast<const f32x4*>(W_out + (size_t)o * 1024 + k0 + quad * 8 + 4);
    bf16x8 bfr;
    bfr[0] = f2bf(w0[0]); bfr[1] = f2bf(w0[1]); bfr[2] = f2bf(w0[2]); bfr[3] = f2bf(w0[3]);
    bfr[4] = f2bf(w1[0]); bfr[5] = f2bf(w1[1]); bfr[6] = f2bf(w1[2]); bfr[7] = f2bf(w1[3]);
#pragma unroll
    for (int mi = 0; mi < 8; ++mi) {
      bf16x8 af = *reinterpret_cast<const bf16x8*>(h + (size_t)(mi * 16 + l16) * 1024 + k0 + quad * 8);
      acc[mi] = __builtin_amdgcn_mfma_f32_16x16x32_bf16(af, bfr, acc[mi], 0, 0, 0);
    }
  }
  const float bias = b_out[o];
#pragma unroll
  for (int mi = 0; mi < 8; ++mi)
#pragma unroll
    for (int r = 0; r < 4; ++r)
      out[(size_t)(mi * 16 + quad * 4 + r) * 1024 + o] = acc[mi][r] + bias;
}

// ---------------------------------------------------------------------------
// Workspace: [0,64MB) P bf16 | +512KB h double buffer | +1KB flags
// ---------------------------------------------------------------------------
extern "C" void kernel_launch(void* const* d_in, const int* in_sizes, int n_in,
                              void* d_out, int out_size, void* d_ws, size_t ws_size,
                              hipStream_t stream) {
  const float* data  = (const float*)d_in[0];
  const float* W_ih  = (const float*)d_in[1];
  const float* W_hh  = (const float*)d_in[2];
  const float* b_i   = (const float*)d_in[3];
  const float* b_h   = (const float*)d_in[4];
  const float* W_out = (const float*)d_in[5];
  const float* b_out = (const float*)d_in[6];
  float* out = (float*)d_out;

  char* ws = (char*)d_ws;
  const size_t OFF_P   = 0;
  const size_t OFF_H   = (size_t)TT * H_ELEMS * 2;   // 67,108,864
  const size_t OFF_FLG = OFF_H + 2 * H_ELEMS * 2;    // +524,288

  __hip_bfloat16* P    = (__hip_bfloat16*)(ws + OFF_P);
  __hip_bfloat16* hbuf = (__hip_bfloat16*)(ws + OFF_H);
  unsigned* flags      = (unsigned*)(ws + OFF_FLG);

  // zero h0/h1 + flags (ws is poisoned 0xAA before every launch)
  hipMemsetAsync(ws + OFF_H, 0, 2 * H_ELEMS * 2 + 2048, stream);

  gemm_xw<<<dim3(8, 256), 256, 0, stream>>>(data, W_ih, b_i, b_h, P);
  rnn_scan3<<<256, 128, 0, stream>>>(P, W_hh, hbuf, flags);
  gemm_out<<<16, 256, 0, stream>>>(hbuf, W_out, b_out, out);  // h[256] in slot 0
}

// Round 5
// 1128.691 us; speedup vs baseline: 4.0442x; 1.6380x over previous
//
#include <hip/hip_runtime.h>
#include <hip/hip_bf16.h>
#include <math.h>

// Elman RNN. T=256, B=128, INP=HS=OUT=1024.
//  0) cvt_data (ws-guarded): data fp32 -> bf16; cvt_tr: W_ih -> W_ihT bf16 [n][k]
//  1) gemm_xw2:  P[t,b,n] = data@W_ih + (b_i+b_h)  (bf16, 64MB ws), lean staging
//  2) rnn_scan5: persistent 256-block kernel, 8 m-groups x 32 n-slices.
//                MALL-only fenceless sync (r3-validated, placement-independent,
//                deterministic). Ht LDS tile XOR-swizzled: conflict-free b128
//                writes AND reads (r3's 1.5e8 conflict cycles -> ~free).
//  3) gemm_out:  out = h_final @ W_out.T + b_out (fp32)
//
// NOTE (r4 lesson): NO XCD-placement-dependent branches. The XCD "fast path"
// tripwired: capture vs replay placement differs, fast-detection was unsound,
// poll guards expired -> timing-dependent output. MALL (sc0 sc1) ops only.

typedef __attribute__((ext_vector_type(8))) short bf16x8;
typedef __attribute__((ext_vector_type(4))) float f32x4;
typedef __attribute__((ext_vector_type(4))) unsigned short u16x4;
typedef __attribute__((ext_vector_type(4))) unsigned int u32x4;
typedef __attribute__((ext_vector_type(2))) unsigned int u32x2;

#define TT 256
#define BB 128
#define HS 1024
#define H_ELEMS (BB * HS)          // 131072

__device__ __forceinline__ short f2bf(float x) {
  __hip_bfloat16 b = __float2bfloat16(x);
  return *reinterpret_cast<short*>(&b);
}
__device__ __forceinline__ float bf2f(unsigned short s) {
  unsigned int u = ((unsigned int)s) << 16;
  float f;
  __builtin_memcpy(&f, &u, 4);
  return f;
}
__device__ __forceinline__ float fast_exp2(float x) {
#if __has_builtin(__builtin_amdgcn_exp2f)
  return __builtin_amdgcn_exp2f(x);
#else
  return exp2f(x);
#endif
}
__device__ __forceinline__ float fast_rcp(float x) {
#if __has_builtin(__builtin_amdgcn_rcpf)
  return __builtin_amdgcn_rcpf(x);
#else
  return 1.0f / x;
#endif
}
__device__ __forceinline__ float fast_tanh(float x) {
  float xc = fminf(fmaxf(x, -9.0f), 9.0f);
  float e = fast_exp2(2.8853900817779268f * xc);
  return (e - 1.0f) * fast_rcp(e + 1.0f);
}

// ---- MALL-direct (sc0 sc1): coherence-point ops, any placement ----
__device__ __forceinline__ void mall_load_b128(u32x4* dst, const void* p) {
  asm volatile("global_load_dwordx4 %0, %1, off sc0 sc1" : "=v"(*dst) : "v"(p) : "memory");
}
__device__ __forceinline__ void mall_store_b64(void* p, u32x2 v) {
  asm volatile("global_store_dwordx2 %0, %1, off sc0 sc1" :: "v"(p), "v"(v) : "memory");
}
__device__ __forceinline__ void mall_store_b32(void* p, unsigned v) {
  asm volatile("global_store_dword %0, %1, off sc0 sc1" :: "v"(p), "v"(v) : "memory");
}
__device__ __forceinline__ unsigned mall_poll_b32(const void* p) {
  unsigned v;
  asm volatile("global_load_dword %0, %1, off sc0 sc1" : "=v"(v) : "v"(p) : "memory");
  asm volatile("s_waitcnt vmcnt(0)" : "+v"(v));
  return v;
}
__device__ __forceinline__ void wait_vm0() {
  asm volatile("s_waitcnt vmcnt(0)" ::: "memory");
}
#define TIE16(d)                                                        \
  asm volatile("s_waitcnt vmcnt(0)"                                     \
               : "+v"(d[0]), "+v"(d[1]), "+v"(d[2]), "+v"(d[3]),        \
                 "+v"(d[4]), "+v"(d[5]), "+v"(d[6]), "+v"(d[7]),        \
                 "+v"(d[8]), "+v"(d[9]), "+v"(d[10]), "+v"(d[11]),      \
                 "+v"(d[12]), "+v"(d[13]), "+v"(d[14]), "+v"(d[15]))

// ---------------------------------------------------------------------------
// cvt_data: fp32 -> bf16, 8 elems/thread. grid 16384 x 256 covers 33.55M.
// ---------------------------------------------------------------------------
__global__ __launch_bounds__(256) void cvt_data(const float* __restrict__ src,
                                                __hip_bfloat16* __restrict__ dst) {
  size_t i = ((size_t)blockIdx.x * 256 + threadIdx.x) * 8;
  f32x4 a = *reinterpret_cast<const f32x4*>(src + i);
  f32x4 b = *reinterpret_cast<const f32x4*>(src + i + 4);
  bf16x8 v;
  v[0] = f2bf(a[0]); v[1] = f2bf(a[1]); v[2] = f2bf(a[2]); v[3] = f2bf(a[3]);
  v[4] = f2bf(b[0]); v[5] = f2bf(b[1]); v[6] = f2bf(b[2]); v[7] = f2bf(b[3]);
  *reinterpret_cast<bf16x8*>(dst + i) = v;
}

// ---------------------------------------------------------------------------
// cvt_tr: W_ihT[n][k] = bf16(W_ih[k][n]). 64x64 LDS tiles, grid (16,16).
// ---------------------------------------------------------------------------
__global__ __launch_bounds__(256) void cvt_tr(const float* __restrict__ src,
                                              __hip_bfloat16* __restrict__ dst) {
  __shared__ __hip_bfloat16 T[64][72];
  const int tid = threadIdx.x;
  const int k0 = blockIdx.y * 64, n0 = blockIdx.x * 64;
  const int r = tid >> 4, c4 = (tid & 15) * 4;
#pragma unroll
  for (int p = 0; p < 4; ++p) {
    int kk = r + p * 16;
    f32x4 v = *reinterpret_cast<const f32x4*>(src + (size_t)(k0 + kk) * 1024 + n0 + c4);
#pragma unroll
    for (int j = 0; j < 4; ++j) T[c4 + j][kk] = __float2bfloat16(v[j]);
  }
  __syncthreads();
  const int rr = tid >> 3, u = tid & 7;
#pragma unroll
  for (int p = 0; p < 2; ++p) {
    int R = rr + p * 32;
    *reinterpret_cast<bf16x8*>(dst + (size_t)(n0 + R) * 1024 + k0 + u * 8) =
        *reinterpret_cast<const bf16x8*>(&T[R][u * 8]);
  }
}

// ---------------------------------------------------------------------------
// Kernel 1: P = A @ W_ihT^T + (b_i+b_h). A = bf16 (ABF) or fp32 (fallback).
// 128x128 tile, 4 waves 64x64, BK=64. Lean staging: b128 load + b128 LDS write.
// Pitch 72 (=9x16B units) rotates bank-quads by row -> 2-way (free) everywhere.
// ---------------------------------------------------------------------------
template <bool ABF>
__global__ __launch_bounds__(256) void gemm_xw2(
    const void* __restrict__ Ain,              // data [32768][1024] bf16 or f32
    const __hip_bfloat16* __restrict__ Bt,     // W_ihT [n][k] bf16
    const float* __restrict__ b_i,
    const float* __restrict__ b_h,
    __hip_bfloat16* __restrict__ P) {
  __shared__ __hip_bfloat16 As[128][72];
  __shared__ __hip_bfloat16 Bs[128][72];

  const int tid = threadIdx.x;
  const int m0 = blockIdx.y * 128, n0 = blockIdx.x * 128;
  const int wave = tid >> 6, lane = tid & 63;
  const int wm = wave & 1, wn = wave >> 1;
  const int quad = lane >> 4, l16 = lane & 15;
  const int sr = tid >> 3, su = tid & 7;

  f32x4 acc[4][4] = {};

  for (int k0 = 0; k0 < 1024; k0 += 64) {
    __syncthreads();
#pragma unroll
    for (int p = 0; p < 4; ++p) {
      int row = sr + p * 32;
      bf16x8 av;
      if (ABF) {
        av = *reinterpret_cast<const bf16x8*>(
            (const __hip_bfloat16*)Ain + (size_t)(m0 + row) * 1024 + k0 + su * 8);
      } else {
        const float* ap = (const float*)Ain + (size_t)(m0 + row) * 1024 + k0 + su * 8;
        f32x4 x = *reinterpret_cast<const f32x4*>(ap);
        f32x4 y = *reinterpret_cast<const f32x4*>(ap + 4);
        av[0] = f2bf(x[0]); av[1] = f2bf(x[1]); av[2] = f2bf(x[2]); av[3] = f2bf(x[3]);
        av[4] = f2bf(y[0]); av[5] = f2bf(y[1]); av[6] = f2bf(y[2]); av[7] = f2bf(y[3]);
      }
      *reinterpret_cast<bf16x8*>(&As[row][su * 8]) = av;
      bf16x8 bv = *reinterpret_cast<const bf16x8*>(
          Bt + (size_t)(n0 + row) * 1024 + k0 + su * 8);
      *reinterpret_cast<bf16x8*>(&Bs[row][su * 8]) = bv;
    }
    __syncthreads();
#pragma unroll
    for (int kk = 0; kk < 2; ++kk) {
      bf16x8 af[4], bfr[4];
#pragma unroll
      for (int mi = 0; mi < 4; ++mi)
        af[mi] = *reinterpret_cast<const bf16x8*>(&As[wm * 64 + mi * 16 + l16][kk * 32 + quad * 8]);
#pragma unroll
      for (int ni = 0; ni < 4; ++ni)
        bfr[ni] = *reinterpret_cast<const bf16x8*>(&Bs[wn * 64 + ni * 16 + l16][kk * 32 + quad * 8]);
#pragma unroll
      for (int mi = 0; mi < 4; ++mi)
#pragma unroll
        for (int ni = 0; ni < 4; ++ni)
          acc[mi][ni] = __builtin_amdgcn_mfma_f32_16x16x32_bf16(af[mi], bfr[ni], acc[mi][ni], 0, 0, 0);
    }
  }

  float bias[4];
#pragma unroll
  for (int ni = 0; ni < 4; ++ni) {
    int col = n0 + wn * 64 + ni * 16 + l16;
    bias[ni] = b_i[col] + b_h[col];
  }
#pragma unroll
  for (int mi = 0; mi < 4; ++mi)
#pragma unroll
    for (int ni = 0; ni < 4; ++ni) {
      int row = m0 + wm * 64 + mi * 16 + quad * 4;
      int col = n0 + wn * 64 + ni * 16 + l16;
#pragma unroll
      for (int r = 0; r < 4; ++r)
        P[(size_t)(row + r) * 1024 + col] = __float2bfloat16(acc[mi][ni][r] + bias[ni]);
    }
}

// ---------------------------------------------------------------------------
// Kernel 2: persistent fenceless scan (MALL-only). 256 blocks x 128 threads.
//   m = blockIdx&7 (16 batch rows), ng = blockIdx>>3 (32 hidden cols).
// Ht swizzle: 16B-unit u of row r stored at u ^ (r&7) ^ (u>>4).
//   writes (r=tid>>3, u=s8+8i): phase quads = s8^r^(i>>1) -> 2-way, free;
//   global loads 128B-coalesced. reads (u=c*16+j*4+quad, row=l16):
//   quads = (j*4+quad)^l16^c -> distinct across phase -> free.
// ---------------------------------------------------------------------------
__global__ __launch_bounds__(128) void rnn_scan5(
    const __hip_bfloat16* __restrict__ P,   // [256][131072]
    const float* __restrict__ W_hh,         // [1024][1024] (k-major)
    __hip_bfloat16* __restrict__ hbuf,      // [2][131072], pre-zeroed
    unsigned* __restrict__ flags) {         // [8][32], pre-zeroed
  __shared__ __hip_bfloat16 Wt[32 * 1024];  // resident W slice [n_local][k] swz
  __shared__ __hip_bfloat16 Ht[16 * 1024];  // h tile, XOR-swizzled
  __shared__ __hip_bfloat16 Cs[16 * 36];    // epilogue transpose staging

  const int tid = threadIdx.x;
  const int m = blockIdx.x & 7;
  const int ng = blockIdx.x >> 3;
  const int m0 = m * 16, n0 = ng * 32;

  // Resident W slice: Wt[nl][k] = W_hh[k][n0+nl]; swizzle sg=(k>>3)^(nl&7).
  for (int i = tid; i < 32 * 1024 / 4; i += 128) {
    int nq = i & 7, k = i >> 3;
    f32x4 v = *reinterpret_cast<const f32x4*>(W_hh + (size_t)k * 1024 + n0 + nq * 4);
#pragma unroll
    for (int j = 0; j < 4; ++j) {
      int nl = nq * 4 + j;
      int sg = (k >> 3) ^ (nl & 7);
      Wt[nl * 1024 + sg * 8 + (k & 7)] = __float2bfloat16(v[j]);
    }
  }
  __syncthreads();

  const int r8 = tid >> 3, s8 = tid & 7;
  const int w = tid >> 6, lane = tid & 63;
  const int quad = lane >> 4, l16 = lane & 15;
  const int nl = w * 16 + l16;
  const int col = n0 + nl;
  const int xorl = l16 & 7;
  const int crow = tid >> 3, cseg = tid & 7;
  unsigned* gflags = flags + m * 32;

  for (int t = 0; t < TT; ++t) {
    const __hip_bfloat16* hc = hbuf + (size_t)(t & 1) * H_ELEMS;
    __hip_bfloat16* hn = hbuf + (size_t)((t + 1) & 1) * H_ELEMS;

    // P_t prefetch BEFORE the poll: HBM latency overlaps the flag wait
    const __hip_bfloat16* Pt =
        P + (size_t)t * H_ELEMS + (size_t)(m0 + quad * 4) * 1024 + col;
    unsigned short pv[4];
#pragma unroll
    for (int r = 0; r < 4; ++r)
      pv[r] = *reinterpret_cast<const unsigned short*>(Pt + (size_t)r * 1024);

    // ---- wait for h_t from all 32 producers of this m-group ----
    if (t > 0) {
      if (tid < 32) {
        const unsigned* fp = gflags + tid;
        int g = 0;
        while (mall_poll_b32(fp) < (unsigned)t && ++g < (1 << 18)) {}
      }
      __syncthreads();
    }

    // ---- load h_t tile (32KB) into swizzled LDS ----
    {
      const char* src = (const char*)(hc + (size_t)(m0 + r8) * 1024) + s8 * 16;
      u32x4 d[16];
#pragma unroll
      for (int i = 0; i < 16; ++i) mall_load_b128(&d[i], src + i * 128);
      TIE16(d);
#pragma unroll
      for (int i = 0; i < 16; ++i) {
        int u = s8 + i * 8;
        int gp = u ^ (r8 & 7) ^ (u >> 4);
        *reinterpret_cast<u32x4*>(&Ht[r8 * 1024 + gp * 8]) = d[i];
      }
    }
    __syncthreads();

    // ---- MFMA: h_tile(16x1024) @ Wslice(1024x32) -> 16x32 ----
    f32x4 acc[4] = {{0.f, 0.f, 0.f, 0.f}, {0.f, 0.f, 0.f, 0.f},
                    {0.f, 0.f, 0.f, 0.f}, {0.f, 0.f, 0.f, 0.f}};
#pragma unroll
    for (int c = 0; c < 8; ++c) {
#pragma unroll
      for (int j = 0; j < 4; ++j) {
        int G = c * 16 + j * 4 + quad;
        int gp = G ^ xorl ^ c;
        bf16x8 af = *reinterpret_cast<const bf16x8*>(&Ht[l16 * 1024 + gp * 8]);
        int sg = G ^ (nl & 7);
        bf16x8 bfrag = *reinterpret_cast<const bf16x8*>(&Wt[nl * 1024 + sg * 8]);
        acc[j] = __builtin_amdgcn_mfma_f32_16x16x32_bf16(af, bfrag, acc[j], 0, 0, 0);
      }
    }

    // ---- epilogue: sum, +P, tanh -> stage (transpose) -> MALL store ----
#pragma unroll
    for (int r = 0; r < 4; ++r) {
      float s = (acc[0][r] + acc[1][r]) + (acc[2][r] + acc[3][r]) + bf2f(pv[r]);
      Cs[(quad * 4 + r) * 36 + nl] = __float2bfloat16(fast_tanh(s));
    }
    __syncthreads();
    {
      u32x2 val = *reinterpret_cast<const u32x2*>(&Cs[crow * 36 + cseg * 4]);
      mall_store_b64(hn + (size_t)(m0 + crow) * 1024 + n0 + cseg * 4, val);
      wait_vm0();  // h stores acked at MALL before flag
    }
    __syncthreads();  // both waves drained

    if (t != TT - 1 && tid == 0)
      mall_store_b32(gflags + ng, (unsigned)(t + 1));
  }
}

// ---------------------------------------------------------------------------
// Kernel 3: out = h_final @ W_out.T + b_out.  (unchanged, validated)
// ---------------------------------------------------------------------------
__global__ __launch_bounds__(256) void gemm_out(
    const __hip_bfloat16* __restrict__ h,   // [128][1024] (hbuf slot 0)
    const float* __restrict__ W_out,        // [1024][1024] row-major [o][k]
    const float* __restrict__ b_out,
    float* __restrict__ out) {              // [128][1024] fp32
  const int tid = threadIdx.x;
  const int wave = tid >> 6, lane = tid & 63;
  const int quad = lane >> 4, l16 = lane & 15;
  const int o = blockIdx.x * 64 + wave * 16 + l16;

  f32x4 acc[8] = {};
  for (int k0 = 0; k0 < 1024; k0 += 32) {
    f32x4 w0 = *reinterpret_cast<const f32x4*>(W_out + (size_t)o * 1024 + k0 + quad * 8);
    f32x4 w1 = *reinterpret_cast<const f32x4*>(W_out + (size_t)o * 1024 + k0 + quad * 8 + 4);
    bf16x8 bfr;
    bfr[0] = f2bf(w0[0]); bfr[1] = f2bf(w0[1]); bfr[2] = f2bf(w0[2]); bfr[3] = f2bf(w0[3]);
    bfr[4] = f2bf(w1[0]); bfr[5] = f2bf(w1[1]); bfr[6] = f2bf(w1[2]); bfr[7] = f2bf(w1[3]);
#pragma unroll
    for (int mi = 0; mi < 8; ++mi) {
      bf16x8 af = *reinterpret_cast<const bf16x8*>(h + (size_t)(mi * 16 + l16) * 1024 + k0 + quad * 8);
      acc[mi] = __builtin_amdgcn_mfma_f32_16x16x32_bf16(af, bfr, acc[mi], 0, 0, 0);
    }
  }
  const float bias = b_out[o];
#pragma unroll
  for (int mi = 0; mi < 8; ++mi)
#pragma unroll
    for (int r = 0; r < 4; ++r)
      out[(size_t)(mi * 16 + quad * 4 + r) * 1024 + o] = acc[mi][r] + bias;
}

// ---------------------------------------------------------------------------
// Workspace layout (bytes):
//   [0, 64MB)        P (bf16)
//   +512KB           h double buffer
//   +1KB             flags
//   +2MB             W_ihT (bf16)
//   +64MB (optional) dataB (bf16)  -- used only if ws_size permits
// ---------------------------------------------------------------------------
extern "C" void kernel_launch(void* const* d_in, const int* in_sizes, int n_in,
                              void* d_out, int out_size, void* d_ws, size_t ws_size,
                              hipStream_t stream) {
  const float* data  = (const float*)d_in[0];
  const float* W_ih  = (const float*)d_in[1];
  const float* W_hh  = (const float*)d_in[2];
  const float* b_i   = (const float*)d_in[3];
  const float* b_h   = (const float*)d_in[4];
  const float* W_out = (const float*)d_in[5];
  const float* b_out = (const float*)d_in[6];
  float* out = (float*)d_out;

  char* ws = (char*)d_ws;
  const size_t OFF_P   = 0;
  const size_t OFF_H   = (size_t)TT * H_ELEMS * 2;        // 67,108,864
  const size_t OFF_FLG = OFF_H + 2 * H_ELEMS * 2;         // +524,288
  const size_t OFF_WT  = OFF_FLG + 1024;                  // W_ihT, 2MB
  const size_t OFF_DB  = OFF_WT + 2u * 1024 * 1024;       // dataB, 64MB
  const size_t NEED_DB = OFF_DB + (size_t)TT * H_ELEMS * 2;

  __hip_bfloat16* P     = (__hip_bfloat16*)(ws + OFF_P);
  __hip_bfloat16* hbuf  = (__hip_bfloat16*)(ws + OFF_H);
  unsigned* flags       = (unsigned*)(ws + OFF_FLG);
  __hip_bfloat16* W_ihT = (__hip_bfloat16*)(ws + OFF_WT);
  __hip_bfloat16* dataB = (__hip_bfloat16*)(ws + OFF_DB);

  // zero h0/h1 + flags (ws is poisoned 0xAA before every launch)
  hipMemsetAsync(ws + OFF_H, 0, 2 * H_ELEMS * 2 + 1024, stream);

  cvt_tr<<<dim3(16, 16), 256, 0, stream>>>(W_ih, W_ihT);
  if (ws_size >= NEED_DB) {
    cvt_data<<<16384, 256, 0, stream>>>(data, dataB);
    gemm_xw2<true><<<dim3(8, 256), 256, 0, stream>>>(dataB, W_ihT, b_i, b_h, P);
  } else {
    gemm_xw2<false><<<dim3(8, 256), 256, 0, stream>>>(data, W_ihT, b_i, b_h, P);
  }
  rnn_scan5<<<256, 128, 0, stream>>>(P, W_hh, hbuf, flags);
  gemm_out<<<16, 256, 0, stream>>>(hbuf, W_out, b_out, out);  // h[256] in slot 0
}